// Round 4
// baseline (16510.597 us; speedup 1.0000x reference)
//
#include <hip/hip_runtime.h>

typedef _Float16 f16x8 __attribute__((ext_vector_type(8)));
typedef _Float16 f16x4 __attribute__((ext_vector_type(4)));
typedef float    f32x4 __attribute__((ext_vector_type(4)));

// Barrier that drains ONLY LDS ops (lgkmcnt), leaving global prefetches
// (vmcnt) in flight.
#define BARRIER() asm volatile("s_waitcnt lgkmcnt(0)\n\ts_barrier" ::: "memory")

__device__ __forceinline__ float sigm(float x) {
    return __builtin_amdgcn_rcpf(1.f + __builtin_exp2f(x * -1.442695041f));
}
__device__ __forceinline__ float tanh_fast(float x) {
    return fmaf(2.f, __builtin_amdgcn_rcpf(1.f + __builtin_exp2f(x * -2.885390082f)), -1.f);
}

// 2 blocks x 16 batches. 7 waves: 0..5 gate waves (unit-group = wave), 6 = head.
// Gate math: gates[384,16] = W_hh[384,96] @ H[96,16] via mfma_f32_16x16x32_f16.
// Wave w owns gate-tiles {w, w+6, w+12, w+18} (16-row tiles), so each lane holds
// i,f,g,o of the SAME 4 units (rows (lane>>4)*4+reg of the tile) for its batch
// column (lane&15) -> c/h update is fully in-register, no cross-lane ops.
__global__ __launch_bounds__(448)
void lstm_fused(
    const float* __restrict__ x,        // [B,T]
    const float* __restrict__ w_ih,     // [384]
    const float* __restrict__ w_hh,     // [384,96]
    const float* __restrict__ b_ih,     // [384]
    const float* __restrict__ b_hh,     // [384]
    const float* __restrict__ w_dense,  // [96]
    const float* __restrict__ b_dense,  // [1]
    float* __restrict__ out,            // [B,T]
    int T)
{
    const int tid  = threadIdx.x;     // 0..447
    const int lane = tid & 63;
    const int wv   = tid >> 6;        // 0..5 gate, 6 head
    const int bb   = blockIdx.x;      // batch group of 16

    // h double-buffered: f16 copy for mfma B-frags, f32 copy for the head.
    // Row strides padded (104 f16 / 100 f32) to break power-of-2 banking.
    __shared__ __align__(16) _Float16 h16[2][16][104];
    __shared__ __align__(16) float    hf32[2][16][100];

    // zero h16[0] (h(-1) = 0): 16*104*2 B = 3328 B = 416 float2
    if (tid < 416) ((float2*)&h16[0][0][0])[tid] = make_float2(0.f, 0.f);

    if (wv < 6) {
        const int r  = lane & 15;     // A-row within tile / batch col (same bits)
        const int g4 = lane >> 4;     // 0..3
        const int b  = lane & 15;     // batch column

        // A-fragments: A[gt][kt], element i = W_hh[96*gt+16*wv + (lane&15)]
        //                                         [kt*32 + (lane>>4)*8 + i]
        f16x8 A[4][3];
        #pragma unroll
        for (int gt = 0; gt < 4; ++gt) {
            const float* rowp = w_hh + (size_t)(96 * gt + 16 * wv + r) * 96;
            #pragma unroll
            for (int kt = 0; kt < 3; ++kt)
                #pragma unroll
                for (int i = 0; i < 8; ++i)
                    A[gt][kt][i] = (_Float16)rowp[kt * 32 + g4 * 8 + i];
        }

        // Per-lane output rows: j = 96*gt + 16*wv + 4*g4 + rg
        float wihv[4][4], biasv[4][4];
        #pragma unroll
        for (int gt = 0; gt < 4; ++gt)
            #pragma unroll
            for (int rg = 0; rg < 4; ++rg) {
                int j = 96 * gt + 16 * wv + 4 * g4 + rg;
                wihv[gt][rg]  = w_ih[j];
                biasv[gt][rg] = b_ih[j] + b_hh[j];
            }

        float c[4] = {0.f, 0.f, 0.f, 0.f};
        const float* xq = x + (size_t)(bb * 16 + b) * T;
        float xs = xq[0];

        __syncthreads();

        #pragma unroll 1
        for (int t = 0; t < T; ++t) {
            int tn = (t + 1 < T) ? t + 1 : T - 1;
            float xs_n = xq[tn];
            const int ib = t & 1, ob = ib ^ 1;

            // B-fragments: B[k = kt*32 + 8*g4 + i][col = b] = h_b[k]
            f16x8 B0 = *(const f16x8*)&h16[ib][b][ 0 + 8 * g4];
            f16x8 B1 = *(const f16x8*)&h16[ib][b][32 + 8 * g4];
            f16x8 B2 = *(const f16x8*)&h16[ib][b][64 + 8 * g4];

            f32x4 D0 = {0.f, 0.f, 0.f, 0.f};
            f32x4 D1 = {0.f, 0.f, 0.f, 0.f};
            f32x4 D2 = {0.f, 0.f, 0.f, 0.f};
            f32x4 D3 = {0.f, 0.f, 0.f, 0.f};
            D0 = __builtin_amdgcn_mfma_f32_16x16x32_f16(A[0][0], B0, D0, 0, 0, 0);
            D1 = __builtin_amdgcn_mfma_f32_16x16x32_f16(A[1][0], B0, D1, 0, 0, 0);
            D2 = __builtin_amdgcn_mfma_f32_16x16x32_f16(A[2][0], B0, D2, 0, 0, 0);
            D3 = __builtin_amdgcn_mfma_f32_16x16x32_f16(A[3][0], B0, D3, 0, 0, 0);
            D0 = __builtin_amdgcn_mfma_f32_16x16x32_f16(A[0][1], B1, D0, 0, 0, 0);
            D1 = __builtin_amdgcn_mfma_f32_16x16x32_f16(A[1][1], B1, D1, 0, 0, 0);
            D2 = __builtin_amdgcn_mfma_f32_16x16x32_f16(A[2][1], B1, D2, 0, 0, 0);
            D3 = __builtin_amdgcn_mfma_f32_16x16x32_f16(A[3][1], B1, D3, 0, 0, 0);
            D0 = __builtin_amdgcn_mfma_f32_16x16x32_f16(A[0][2], B2, D0, 0, 0, 0);
            D1 = __builtin_amdgcn_mfma_f32_16x16x32_f16(A[1][2], B2, D1, 0, 0, 0);
            D2 = __builtin_amdgcn_mfma_f32_16x16x32_f16(A[2][2], B2, D2, 0, 0, 0);
            D3 = __builtin_amdgcn_mfma_f32_16x16x32_f16(A[3][2], B2, D3, 0, 0, 0);

            float iv[4], fv[4], gv[4], ov[4];
            #pragma unroll
            for (int rg = 0; rg < 4; ++rg)
                iv[rg] = sigm(fmaf(xs, wihv[0][rg], D0[rg] + biasv[0][rg]));
            #pragma unroll
            for (int rg = 0; rg < 4; ++rg)
                fv[rg] = sigm(fmaf(xs, wihv[1][rg], D1[rg] + biasv[1][rg]));
            #pragma unroll
            for (int rg = 0; rg < 4; ++rg)
                gv[rg] = tanh_fast(fmaf(xs, wihv[2][rg], D2[rg] + biasv[2][rg]));
            #pragma unroll
            for (int rg = 0; rg < 4; ++rg)
                ov[rg] = sigm(fmaf(xs, wihv[3][rg], D3[rg] + biasv[3][rg]));

            f16x4 hp;
            float4 hq;
            #pragma unroll
            for (int rg = 0; rg < 4; ++rg) {
                c[rg] = fmaf(fv[rg], c[rg], iv[rg] * gv[rg]);
                float th = tanh_fast(c[rg]);
                float h  = ov[rg] * th;
                hp[rg] = (_Float16)h;
                (&hq.x)[rg] = h;
            }
            *(f16x4*)&h16[ob][b][16 * wv + 4 * g4]  = hp;
            *(float4*)&hf32[ob][b][16 * wv + 4 * g4] = hq;

            BARRIER();
            xs = xs_n;
        }
    } else {
        // ---- head wave: out[b][t] = w_dense . h(t) + bd, lagged one step ----
        const int b   = lane & 15;
        const int seg = lane >> 4;    // 24-element segment of the 96-dot
        float wdv[24];
        #pragma unroll
        for (int m = 0; m < 24; ++m) wdv[m] = w_dense[seg * 24 + m];
        const float bd = b_dense[0];
        float* orow = out + (size_t)(bb * 16 + b) * T;

        __syncthreads();

        #pragma unroll 1
        for (int t = 0; t < T; ++t) {
            if (t) {
                const int ib = t & 1;            // buffer holding h(t-1)
                const float4* hr = (const float4*)&hf32[ib][b][seg * 24];
                float a0 = 0.f, a1 = 0.f;
                #pragma unroll
                for (int q = 0; q < 6; q += 2) {
                    float4 u = hr[q], v = hr[q + 1];
                    a0 = fmaf(u.w, wdv[q*4+3], fmaf(u.z, wdv[q*4+2],
                         fmaf(u.y, wdv[q*4+1], fmaf(u.x, wdv[q*4+0], a0))));
                    a1 = fmaf(v.w, wdv[q*4+7], fmaf(v.z, wdv[q*4+6],
                         fmaf(v.y, wdv[q*4+5], fmaf(v.x, wdv[q*4+4], a1))));
                }
                float v = a0 + a1;
                v += __shfl_xor(v, 16, 64);
                v += __shfl_xor(v, 32, 64);
                if (lane < 16) orow[t - 1] = v + bd;
            }
            BARRIER();
        }
        // tail: h(T-1) lives in buffer (T & 1)
        {
            const int ib = T & 1;
            const float4* hr = (const float4*)&hf32[ib][b][seg * 24];
            float a0 = 0.f, a1 = 0.f;
            #pragma unroll
            for (int q = 0; q < 6; q += 2) {
                float4 u = hr[q], v = hr[q + 1];
                a0 = fmaf(u.w, wdv[q*4+3], fmaf(u.z, wdv[q*4+2],
                     fmaf(u.y, wdv[q*4+1], fmaf(u.x, wdv[q*4+0], a0))));
                a1 = fmaf(v.w, wdv[q*4+7], fmaf(v.z, wdv[q*4+6],
                     fmaf(v.y, wdv[q*4+5], fmaf(v.x, wdv[q*4+4], a1))));
            }
            float v = a0 + a1;
            v += __shfl_xor(v, 16, 64);
            v += __shfl_xor(v, 32, 64);
            if (lane < 16) orow[T - 1] = v + bd;
        }
    }
}

extern "C" void kernel_launch(void* const* d_in, const int* in_sizes, int n_in,
                              void* d_out, int out_size, void* d_ws, size_t ws_size,
                              hipStream_t stream) {
    const float* x   = (const float*)d_in[0];
    const float* wih = (const float*)d_in[1];
    const float* whh = (const float*)d_in[2];
    const float* bih = (const float*)d_in[3];
    const float* bhh = (const float*)d_in[4];
    const float* wd  = (const float*)d_in[5];
    const float* bd  = (const float*)d_in[6];
    float* out = (float*)d_out;

    const int B = 32;
    const int T = in_sizes[0] / B;   // x is [B,T,1]

    lstm_fused<<<dim3(B / 16), dim3(448), 0, stream>>>(x, wih, whh, bih, bhh, wd, bd, out, T);
}

// Round 5
// 7999.490 us; speedup vs baseline: 2.0640x; 2.0640x over previous
//
#include <hip/hip_runtime.h>

typedef _Float16 h2 __attribute__((ext_vector_type(2)));

__device__ __forceinline__ h2 mkh2(float a, float b) {
    h2 r; r.x = (_Float16)a; r.y = (_Float16)b; return r;
}
__device__ __forceinline__ h2 bc(unsigned u) {
    union { unsigned u; h2 h; } c; c.u = u; return c.h;
}

// DPP quad-perm lane exchange (VALU, no LDS): 0xB1 = swap lane^1
template <int CTRL>
__device__ __forceinline__ float dpp_q(float v) {
    int i = __builtin_bit_cast(int, v);
    int r = __builtin_amdgcn_update_dpp(0, i, CTRL, 0xF, 0xF, true);
    return __builtin_bit_cast(float, r);
}

// Barrier that drains ONLY LDS ops (lgkmcnt), leaving global prefetches
// (vmcnt) in flight.
#define BARRIER() asm volatile("s_waitcnt lgkmcnt(0)\n\ts_barrier" ::: "memory")

// 8 fdot2: one uint4 of h (8 halves) against row-A and row-B weight pairs.
#define DOT8(Q, i) do {                                               \
    aA0 = __builtin_amdgcn_fdot2(WA[4*i+0], bc(Q.x), aA0, false);     \
    aA1 = __builtin_amdgcn_fdot2(WA[4*i+1], bc(Q.y), aA1, false);     \
    aA2 = __builtin_amdgcn_fdot2(WA[4*i+2], bc(Q.z), aA2, false);     \
    aA3 = __builtin_amdgcn_fdot2(WA[4*i+3], bc(Q.w), aA3, false);     \
    aB0 = __builtin_amdgcn_fdot2(WB[4*i+0], bc(Q.x), aB0, false);     \
    aB1 = __builtin_amdgcn_fdot2(WB[4*i+1], bc(Q.y), aB1, false);     \
    aB2 = __builtin_amdgcn_fdot2(WB[4*i+2], bc(Q.z), aB2, false);     \
    aB3 = __builtin_amdgcn_fdot2(WB[4*i+3], bc(Q.w), aB3, false);     \
} while (0)

// 96-wide f32 dot of one LDS history row against w_dense.
__device__ __forceinline__ float head_dot(const float* hrow, const float* wdp) {
    const float4* hr = reinterpret_cast<const float4*>(hrow);
    const float4* wv = reinterpret_cast<const float4*>(wdp);
    float a0 = 0.f, a1 = 0.f, a2 = 0.f, a3 = 0.f;
    #pragma unroll
    for (int k = 0; k < 24; k += 4) {
        float4 ha = hr[k], hb = hr[k + 1], hc = hr[k + 2], hd = hr[k + 3];
        float4 wa = wv[k], wb = wv[k + 1], wc = wv[k + 2], wd = wv[k + 3];
        a0 = fmaf(ha.w, wa.w, fmaf(ha.z, wa.z, fmaf(ha.y, wa.y, fmaf(ha.x, wa.x, a0))));
        a1 = fmaf(hb.w, wb.w, fmaf(hb.z, wb.z, fmaf(hb.y, wb.y, fmaf(hb.x, wb.x, a1))));
        a2 = fmaf(hc.w, wc.w, fmaf(hc.z, wc.z, fmaf(hc.y, wc.y, fmaf(hc.x, wc.x, a2))));
        a3 = fmaf(hd.w, wd.w, fmaf(hd.z, wd.z, fmaf(hd.y, wd.y, fmaf(hd.x, wd.x, a3))));
    }
    return (a0 + a1) + (a2 + a3);
}

// 4 waves: 0..2 gate waves (each lane owns TWO w_hh rows), 3 = head.
// Lane (u, p): u = 32*wv + (lane>>1), p = lane&1.
//   p==0 computes rows u (i, sigmoid)      and 192+u (g, tanh)
//   p==1 computes rows 96+u (f, sigmoid)   and 288+u (o, sigmoid)
// One DPP xor1 swap delivers (f,o) to the p==0 lane, which owns c/h of unit u.
__global__ __launch_bounds__(256)
void lstm_fused(
    const float* __restrict__ x,        // [B,T]
    const float* __restrict__ w_ih,     // [384]
    const float* __restrict__ w_hh,     // [384,96]
    const float* __restrict__ b_ih,     // [384]
    const float* __restrict__ b_hh,     // [384]
    const float* __restrict__ w_dense,  // [96]
    const float* __restrict__ b_dense,  // [1]
    float* __restrict__ out,            // [B,T]
    int T)
{
    const int tid  = threadIdx.x;    // 0..255
    const int lane = tid & 63;
    const int wv   = tid >> 6;       // 0..2 gate, 3 head

    // Double-buffered h (f16, broadcast-read).
    __shared__ __align__(16) _Float16 hbuf[2][96];
    // 64-step h history (f32) for the dense head.
    __shared__ __align__(16) float hist[2][64][100];

    if (tid < 96) { hbuf[0][tid] = (_Float16)0.f; hbuf[1][tid] = (_Float16)0.f; }

    const float* xrow = x + (size_t)blockIdx.x * T;
    float*       orow = out + (size_t)blockIdx.x * T;

    __syncthreads();

    if (wv < 3) {
        const int p = lane & 1;
        const int u = (wv << 5) | (lane >> 1);   // hidden unit 0..95
        const int rowA = 96 * p + u;             // p0: i-row, p1: f-row
        const int rowB = 96 * (2 + p) + u;       // p0: g-row, p1: o-row

        // Weights for both rows as packed-f16 pairs in VGPRs (48 + 48 h2).
        h2 WA[48], WB[48];
        {
            const float4* ra = reinterpret_cast<const float4*>(w_hh + (size_t)rowA * 96);
            const float4* rb = reinterpret_cast<const float4*>(w_hh + (size_t)rowB * 96);
            #pragma unroll
            for (int q = 0; q < 24; ++q) {
                float4 fa = ra[q];
                WA[2*q]   = mkh2(fa.x, fa.y);
                WA[2*q+1] = mkh2(fa.z, fa.w);
            }
            #pragma unroll
            for (int q = 0; q < 24; ++q) {
                float4 fb = rb[q];
                WB[2*q]   = mkh2(fb.x, fb.y);
                WB[2*q+1] = mkh2(fb.z, fb.w);
            }
        }

        const float wihA  = w_ih[rowA];
        const float wihB  = w_ih[rowB];
        const float biasA = b_ih[rowA] + b_hh[rowA];
        const float biasB = b_ih[rowB] + b_hh[rowB];
        // Row B is tanh only for p==0 (gate g): tanh(x) = 2*sig(2x)-1.
        const float nkB = (p == 0) ? -2.885390082f : -1.442695041f;
        const float m1B = (p == 0) ? 2.f : 1.f;
        const float d1B = (p == 0) ? -1.f : 0.f;

        float c  = 0.f;
        float xs = xrow[0];

        #pragma unroll 1
        for (int t = 0; t < T; ++t) {
            int tn = (t + 1 < T) ? t + 1 : T - 1;
            float xs_n = xrow[tn];

            const uint4* hp = reinterpret_cast<const uint4*>(hbuf[(t & 1) ^ 1]);
            float aA0 = 0.f, aA1 = 0.f, aA2 = 0.f, aA3 = 0.f;
            float aB0 = 0.f, aB1 = 0.f, aB2 = 0.f, aB3 = 0.f;
            uint4 qA = hp[0], qB = hp[1], qC = hp[2];
            DOT8(qA, 0);  qA = hp[3];
            DOT8(qB, 1);  qB = hp[4];
            DOT8(qC, 2);  qC = hp[5];
            DOT8(qA, 3);  qA = hp[6];
            DOT8(qB, 4);  qB = hp[7];
            DOT8(qC, 5);  qC = hp[8];
            DOT8(qA, 6);  qA = hp[9];
            DOT8(qB, 7);  qB = hp[10];
            DOT8(qC, 8);  qC = hp[11];
            DOT8(qA, 9);
            DOT8(qB, 10);
            DOT8(qC, 11);

            float vA = (aA0 + aA1) + (aA2 + aA3);
            float vB = (aB0 + aB1) + (aB2 + aB3);
            float preA = vA + fmaf(xs, wihA, biasA);
            float preB = vB + fmaf(xs, wihB, biasB);
            // row A is always sigmoid
            float actA = __builtin_amdgcn_rcpf(1.f + __builtin_exp2f(preA * -1.442695041f));
            float actB = fmaf(m1B, __builtin_amdgcn_rcpf(1.f + __builtin_exp2f(preB * nkB)), d1B);

            // pair swap: p0 receives (f, o) from p1
            float oA = dpp_q<0xB1>(actA);
            float oB = dpp_q<0xB1>(actB);

            if (p == 0) {   // owns unit u: actA=i, actB=g, oA=f, oB=o
                c = fmaf(oA, c, actA * actB);
                float th = fmaf(2.f, __builtin_amdgcn_rcpf(1.f + __builtin_exp2f(c * -2.885390082f)), -1.f);
                float h  = oB * th;
                hbuf[t & 1][u] = (_Float16)h;          // matvec path (f16)
                hist[(t >> 6) & 1][t & 63][u] = h;     // head path (f32)
            }
            BARRIER();
            xs = xs_n;
        }
    } else {
        // ---- head wave: one burst of 64 outputs per 64-step window ----
        const float bd = b_dense[0];
        #pragma unroll 1
        for (int t = 0; t < T; ++t) {
            if (t && (t & 63) == 0) {
                const int buf = ((t >> 6) - 1) & 1;    // completed window's buffer
                float a = head_dot(&hist[buf][lane][0], w_dense);
                orow[t - 64 + lane] = a + bd;
            }
            BARRIER();
        }
        // tail: rows [T0, T)
        const int T0 = ((T - 1) >> 6) << 6;
        if (lane < T - T0) {
            const int buf = (T0 >> 6) & 1;
            float a = head_dot(&hist[buf][lane][0], w_dense);
            orow[T0 + lane] = a + bd;
        }
    }
}

extern "C" void kernel_launch(void* const* d_in, const int* in_sizes, int n_in,
                              void* d_out, int out_size, void* d_ws, size_t ws_size,
                              hipStream_t stream) {
    const float* x   = (const float*)d_in[0];
    const float* wih = (const float*)d_in[1];
    const float* whh = (const float*)d_in[2];
    const float* bih = (const float*)d_in[3];
    const float* bhh = (const float*)d_in[4];
    const float* wd  = (const float*)d_in[5];
    const float* bd  = (const float*)d_in[6];
    float* out = (float*)d_out;

    const int B = 32;
    const int T = in_sizes[0] / B;   // x is [B,T,1]

    lstm_fused<<<dim3(B), dim3(256), 0, stream>>>(x, wih, whh, bih, bhh, wd, bd, out, T);
}